// Round 13
// baseline (495.899 us; speedup 1.0000x reference)
//
#include <hip/hip_runtime.h>
#include <math.h>

#define BATCH 256
#define TX 512
#define TS 512
#define DH 128

typedef _Float16 f16x8 __attribute__((ext_vector_type(8)));
typedef _Float16 f16x4 __attribute__((ext_vector_type(4)));
typedef float f32x4 __attribute__((ext_vector_type(4)));

__device__ __forceinline__ float sigf(float x) {
    return __builtin_amdgcn_rcpf(1.0f + __expf(-x));
}
__device__ __forceinline__ float tanhfast(float x) {
    return fmaf(-2.0f, __builtin_amdgcn_rcpf(__expf(2.0f * x) + 1.0f), 1.0f);
}
template<int CTRL>
__device__ __forceinline__ float dpp_f32(float x) {
    return __int_as_float(__builtin_amdgcn_update_dpp(
        0, __float_as_int(x), CTRL, 0xF, 0xF, true));
}
#define DPP_BC0  0x00
#define DPP_BC1  0x55
#define DPP_BC2  0xAA

// ============ fully fused: enc_pre + enc + traj + MFMA decoder ===============
// One WG (512 thr, 8 waves) per batch element.
// Decoder: wave w owns h-cols [16w,16w+16). Per step: 16 MFMA 16x16x32_f16
// (4 gates x 4 K-tiles). A = Whh frags (64 VGPR, row = lane&15 -> col 16w+row).
// B = h replicated across N (broadcast LDS read; N-layout then irrelevant).
// C-init = per-step s-dot + bias + z term, precomputed 64 steps at a time into
// LDS (sgate). D read via verified mapping row=(l>>4)*4+r, col=l&15: lane
// handles jj = 16w + 4*(l>>4) + (l&3) (4x redundant across l&12).
__global__ __launch_bounds__(512) void fused_kernel(
    const float* __restrict__ x, const float* __restrict__ s,
    const float* __restrict__ h0, const float* __restrict__ c0,
    const float* __restrict__ We_ih, const float* __restrict__ We_hh,
    const float* __restrict__ be_ih, const float* __restrict__ be_hh,
    const float* __restrict__ Wfc_e, const float* __restrict__ bfc_e,
    const float* __restrict__ Wd_ih, const float* __restrict__ Wd_hh,
    const float* __restrict__ bd_ih, const float* __restrict__ bd_hh,
    const float* __restrict__ Wfc_d, const float* __restrict__ bfc_d,
    float* __restrict__ out_z, float* __restrict__ out_traj,
    float* __restrict__ out_h)
{
    __shared__ __align__(16) float pre_lds[TX][12];     // 24576 B
    __shared__ __align__(16) _Float16 sgate[64][516];   // 66048 B (stride 1032B: 8-aligned, banks ok)
    __shared__ __align__(16) _Float16 hbuf[2][DH];      // 512 B
    __shared__ float base_lds[4 * DH];                  // 2048 B
    __shared__ float s_stage[64][8];                    // 2048 B
    __shared__ float zslot;

    const int b    = blockIdx.x;
    const int tid  = threadIdx.x;
    const int w    = tid >> 6;     // wave 0..7
    const int l    = tid & 63;
    const int p    = l >> 4;       // 0..3
    const int rsel = l & 3;
    const int jj   = 16 * w + 4 * p + rsel;   // this lane's h-col
    const bool writer = ((l & 12) == 0);

    // ---- phase A: encoder x-gates into LDS (thread tid = timestep) ----
    {
        const float* xp = x + ((size_t)b * TX + tid) * 8;
        const float4 x0 = *(const float4*)(xp);
        const float4 x1 = *(const float4*)(xp + 4);
        float o[12];
        #pragma unroll
        for (int g = 0; g < 4; ++g) {
            #pragma unroll
            for (int kk = 0; kk < 3; ++kk) {
                const int row = g * 3 + kk;
                const float* wr = We_ih + row * 8;
                float d = be_ih[row] + be_hh[row];
                d = fmaf(wr[0], x0.x, d); d = fmaf(wr[1], x0.y, d);
                d = fmaf(wr[2], x0.z, d); d = fmaf(wr[3], x0.w, d);
                d = fmaf(wr[4], x1.x, d); d = fmaf(wr[5], x1.y, d);
                d = fmaf(wr[6], x1.z, d); d = fmaf(wr[7], x1.w, d);
                o[kk * 4 + g] = d;
            }
        }
        float* op = pre_lds[tid];
        *(float4*)(op)     = make_float4(o[0], o[1], o[2],  o[3]);
        *(float4*)(op + 4) = make_float4(o[4], o[5], o[6],  o[7]);
        *(float4*)(op + 8) = make_float4(o[8], o[9], o[10], o[11]);
    }
    if (tid < DH) hbuf[0][tid] = (_Float16)0.0f;

    // ---- traj_hat (independent of z) ----
    {
        const float* st = s + ((size_t)b * TS + tid) * 6;
        const float2 sa  = *(const float2*)(st);
        const float2 sbb = *(const float2*)(st + 2);
        const float2 sc  = *(const float2*)(st + 4);
        float o0 = bfc_d[0];
        o0 = fmaf(sa.x,  Wfc_d[0], o0); o0 = fmaf(sa.y,  Wfc_d[1], o0);
        o0 = fmaf(sbb.x, Wfc_d[2], o0); o0 = fmaf(sbb.y, Wfc_d[3], o0);
        o0 = fmaf(sc.x,  Wfc_d[4], o0); o0 = fmaf(sc.y,  Wfc_d[5], o0);
        float o1 = bfc_d[1];
        o1 = fmaf(sa.x,  Wfc_d[6],  o1); o1 = fmaf(sa.y,  Wfc_d[7],  o1);
        o1 = fmaf(sbb.x, Wfc_d[8],  o1); o1 = fmaf(sbb.y, Wfc_d[9],  o1);
        o1 = fmaf(sc.x,  Wfc_d[10], o1); o1 = fmaf(sc.y,  Wfc_d[11], o1);
        *(float2*)(out_traj + ((size_t)b * TS + tid) * 2) = make_float2(o0, o1);
    }

    // ---- decoder A-fragments: Whh rows (gate g, col 16w + (l&15)), f16 ----
    f16x8 Afrag[4][4];
    #pragma unroll
    for (int g = 0; g < 4; ++g) {
        #pragma unroll
        for (int kt = 0; kt < 4; ++kt) {
            const float* wp = Wd_hh + (size_t)(g * DH + 16 * w + (l & 15)) * DH
                              + kt * 32 + p * 8;
            const float4 lo = *(const float4*)(wp);
            const float4 hi = *(const float4*)(wp + 4);
            f16x8 a;
            a[0] = (_Float16)lo.x; a[1] = (_Float16)lo.y;
            a[2] = (_Float16)lo.z; a[3] = (_Float16)lo.w;
            a[4] = (_Float16)hi.x; a[5] = (_Float16)hi.y;
            a[6] = (_Float16)hi.z; a[7] = (_Float16)hi.w;
            Afrag[g][kt] = a;
        }
    }

    __syncthreads();   // pre_lds + hbuf[0] ready

    // ---- phase B: serial encoder on lanes 0..3 of wave 0 ----
    if (tid < 4) {
        const int kk = (tid < 3) ? tid : 0;
        float wh[4][3];
        #pragma unroll
        for (int g = 0; g < 4; ++g) {
            const int row = g * 3 + kk;
            #pragma unroll
            for (int n = 0; n < 3; ++n) wh[g][n] = We_hh[row * 3 + n];
        }
        float hv0 = h0[b * 3 + 0], hv1 = h0[b * 3 + 1], hv2 = h0[b * 3 + 2];
        float c = c0[b * 3 + kk];

        float4 P = *(const float4*)(&pre_lds[0][kk * 4]);
        for (int t = 0; t < TX; ++t) {
            const int tn = (t + 1 < TX) ? t + 1 : t;
            const float4 Pn = *(const float4*)(&pre_lds[tn][kk * 4]);

            float a0 = P.x, a1 = P.y, a2 = P.z, a3 = P.w;   // i,f,g,o
            a0 = fmaf(wh[0][0], hv0, a0); a0 = fmaf(wh[0][1], hv1, a0); a0 = fmaf(wh[0][2], hv2, a0);
            a1 = fmaf(wh[1][0], hv0, a1); a1 = fmaf(wh[1][1], hv1, a1); a1 = fmaf(wh[1][2], hv2, a1);
            a2 = fmaf(wh[2][0], hv0, a2); a2 = fmaf(wh[2][1], hv1, a2); a2 = fmaf(wh[2][2], hv2, a2);
            a3 = fmaf(wh[3][0], hv0, a3); a3 = fmaf(wh[3][1], hv1, a3); a3 = fmaf(wh[3][2], hv2, a3);

            const float ig = sigf(a0);
            const float fg = sigf(a1);
            const float gg = tanhfast(a2);
            const float og = sigf(a3);
            c = fmaf(fg, c, ig * gg);
            const float hk = og * tanhfast(c);
            hv0 = dpp_f32<DPP_BC0>(hk);
            hv1 = dpp_f32<DPP_BC1>(hk);
            hv2 = dpp_f32<DPP_BC2>(hk);
            P = Pn;
        }
        if (tid == 0) {
            float zz = bfc_e[0];
            zz = fmaf(hv0, Wfc_e[0], zz);
            zz = fmaf(hv1, Wfc_e[1], zz);
            zz = fmaf(hv2, Wfc_e[2], zz);
            zslot = zz;
            out_z[b] = zz;
        }
    }
    __syncthreads();   // z ready

    // per-row constant part of the gates: bias + z * w6
    base_lds[tid] = bd_ih[tid] + bd_hh[tid] + zslot * Wd_ih[(size_t)tid * 7 + 6];

    // ---- phase C: MFMA decoder ----
    float c = 0.0f, hn = 0.0f;
    const int row_r = 64 * w + l;               // refill row for this thread
    const float* wi = Wd_ih + (size_t)row_r * 7;
    const float rw0 = wi[0], rw1 = wi[1], rw2 = wi[2];
    const float rw3 = wi[3], rw4 = wi[4], rw5 = wi[5];

    for (int chunk = 0; chunk < TS / 64; ++chunk) {
        // stage s chunk into LDS
        {
            const int tl = tid >> 3, e = tid & 7;
            if (e < 6)
                s_stage[tl][e] = s[((size_t)b * TS + chunk * 64 + tl) * 6 + e];
        }
        __syncthreads();   // s_stage + base_lds ready; prev chunk's sgate reads done
        // refill sgate[tl][row] = base + Wd_ih[row,0:6] . s_t
        {
            const float bs = base_lds[row_r];
            for (int tl = 0; tl < 64; ++tl) {
                float a = bs;
                a = fmaf(rw0, s_stage[tl][0], a);
                a = fmaf(rw1, s_stage[tl][1], a);
                a = fmaf(rw2, s_stage[tl][2], a);
                a = fmaf(rw3, s_stage[tl][3], a);
                a = fmaf(rw4, s_stage[tl][4], a);
                a = fmaf(rw5, s_stage[tl][5], a);
                sgate[tl][row_r] = (_Float16)a;
            }
        }
        __syncthreads();

        for (int tl = 0; tl < 64; ++tl) {
            const int t   = chunk * 64 + tl;
            const int cur = t & 1;

            // B fragments: h replicated over N (address depends on p only)
            const f16x8* hb = (const f16x8*)(&hbuf[cur][0]);
            const f16x8 B0 = hb[p];
            const f16x8 B1 = hb[4 + p];
            const f16x8 B2 = hb[8 + p];
            const f16x8 B3 = hb[12 + p];

            // C init from sgate (rows 16w+4p .. +4, one b64 per gate)
            const _Float16* sgp = &sgate[tl][16 * w + 4 * p];
            const f16x4 s0 = *(const f16x4*)(sgp);
            const f16x4 s1 = *(const f16x4*)(sgp + DH);
            const f16x4 s2 = *(const f16x4*)(sgp + 2 * DH);
            const f16x4 s3 = *(const f16x4*)(sgp + 3 * DH);
            f32x4 C0 = {(float)s0[0], (float)s0[1], (float)s0[2], (float)s0[3]};
            f32x4 C1 = {(float)s1[0], (float)s1[1], (float)s1[2], (float)s1[3]};
            f32x4 C2 = {(float)s2[0], (float)s2[1], (float)s2[2], (float)s2[3]};
            f32x4 C3 = {(float)s3[0], (float)s3[1], (float)s3[2], (float)s3[3]};

            C0 = __builtin_amdgcn_mfma_f32_16x16x32_f16(Afrag[0][0], B0, C0, 0, 0, 0);
            C1 = __builtin_amdgcn_mfma_f32_16x16x32_f16(Afrag[1][0], B0, C1, 0, 0, 0);
            C2 = __builtin_amdgcn_mfma_f32_16x16x32_f16(Afrag[2][0], B0, C2, 0, 0, 0);
            C3 = __builtin_amdgcn_mfma_f32_16x16x32_f16(Afrag[3][0], B0, C3, 0, 0, 0);
            C0 = __builtin_amdgcn_mfma_f32_16x16x32_f16(Afrag[0][1], B1, C0, 0, 0, 0);
            C1 = __builtin_amdgcn_mfma_f32_16x16x32_f16(Afrag[1][1], B1, C1, 0, 0, 0);
            C2 = __builtin_amdgcn_mfma_f32_16x16x32_f16(Afrag[2][1], B1, C2, 0, 0, 0);
            C3 = __builtin_amdgcn_mfma_f32_16x16x32_f16(Afrag[3][1], B1, C3, 0, 0, 0);
            C0 = __builtin_amdgcn_mfma_f32_16x16x32_f16(Afrag[0][2], B2, C0, 0, 0, 0);
            C1 = __builtin_amdgcn_mfma_f32_16x16x32_f16(Afrag[1][2], B2, C1, 0, 0, 0);
            C2 = __builtin_amdgcn_mfma_f32_16x16x32_f16(Afrag[2][2], B2, C2, 0, 0, 0);
            C3 = __builtin_amdgcn_mfma_f32_16x16x32_f16(Afrag[3][2], B2, C3, 0, 0, 0);
            C0 = __builtin_amdgcn_mfma_f32_16x16x32_f16(Afrag[0][3], B3, C0, 0, 0, 0);
            C1 = __builtin_amdgcn_mfma_f32_16x16x32_f16(Afrag[1][3], B3, C1, 0, 0, 0);
            C2 = __builtin_amdgcn_mfma_f32_16x16x32_f16(Afrag[2][3], B3, C2, 0, 0, 0);
            C3 = __builtin_amdgcn_mfma_f32_16x16x32_f16(Afrag[3][3], B3, C3, 0, 0, 0);

            // select this lane's row (r = rsel) from the verified D layout
            const float pi = rsel == 0 ? C0[0] : rsel == 1 ? C0[1] : rsel == 2 ? C0[2] : C0[3];
            const float pf = rsel == 0 ? C1[0] : rsel == 1 ? C1[1] : rsel == 2 ? C1[2] : C1[3];
            const float pg = rsel == 0 ? C2[0] : rsel == 1 ? C2[1] : rsel == 2 ? C2[2] : C2[3];
            const float po = rsel == 0 ? C3[0] : rsel == 1 ? C3[1] : rsel == 2 ? C3[2] : C3[3];

            const float ig = sigf(pi);
            const float fg = sigf(pf);
            const float gg = tanhfast(pg);
            const float og = sigf(po);
            c  = fmaf(fg, c, ig * gg);
            hn = og * tanhfast(c);

            if (writer) hbuf[cur ^ 1][jj] = (_Float16)hn;
            __syncthreads();
        }
    }

    if (writer) out_h[(size_t)b * DH + jj] = hn;
}

extern "C" void kernel_launch(void* const* d_in, const int* in_sizes, int n_in,
                              void* d_out, int out_size, void* d_ws, size_t ws_size,
                              hipStream_t stream) {
    const float* x      = (const float*)d_in[0];
    const float* s      = (const float*)d_in[1];
    const float* h0     = (const float*)d_in[2];
    const float* c0     = (const float*)d_in[3];
    const float* We_ih  = (const float*)d_in[4];
    const float* We_hh  = (const float*)d_in[5];
    const float* be_ih  = (const float*)d_in[6];
    const float* be_hh  = (const float*)d_in[7];
    const float* Wfc_e  = (const float*)d_in[8];
    const float* bfc_e  = (const float*)d_in[9];
    const float* Wd_ih  = (const float*)d_in[10];
    const float* Wd_hh  = (const float*)d_in[11];
    const float* bd_ih  = (const float*)d_in[12];
    const float* bd_hh  = (const float*)d_in[13];
    const float* Wfc_d  = (const float*)d_in[14];
    const float* bfc_d  = (const float*)d_in[15];

    float* out      = (float*)d_out;
    float* out_z    = out;                           // [256]
    float* out_traj = out + BATCH;                   // [256*512*2]
    float* out_h    = out + BATCH + BATCH * TS * 2;  // [256*128]

    fused_kernel<<<BATCH, 512, 0, stream>>>(
        x, s, h0, c0, We_ih, We_hh, be_ih, be_hh, Wfc_e, bfc_e,
        Wd_ih, Wd_hh, bd_ih, bd_hh, Wfc_d, bfc_d,
        out_z, out_traj, out_h);
}